// Round 11
// baseline (609.635 us; speedup 1.0000x reference)
//
#include <hip/hip_runtime.h>

typedef __attribute__((ext_vector_type(8))) _Float16 f16x8;
typedef __attribute__((ext_vector_type(4))) _Float16 f16x4;
typedef __attribute__((ext_vector_type(4))) float f32x4;

#define DI __device__ __forceinline__
// Raw barrier: LDS-drain only (lgkmcnt). Avoids the compiler's vmcnt(0) drain.
#define BAR() asm volatile("s_waitcnt lgkmcnt(0)\n\ts_barrier" ::: "memory")

DI f32x4 mfma16(f16x8 a, f16x8 b, f32x4 c) {
    return __builtin_amdgcn_mfma_f32_16x16x32_f16(a, b, c, 0, 0, 0);
}

// Wave-mapping: wave w owns features [w*32, w*32+32) for layers 0/1 (2 n-tiles,
// weight frags reused across all MH m-groups of 16 rows). Layer 2: wave w computes
// rows (w>>1)*16 (+32*g) and cols (w&1)*16 of the MHx16 x 32 output.
// LDS aliasing: the X staging buffer and H1 share one allocation (disjoint
// lifetimes separated by l01's first internal barrier); loops need an end barrier.

template <int NK>
DI void load_wf2(const _Float16* __restrict__ wt, int Kp, int nbase, int l16, int q,
                 f16x8 f[NK][2]) {
#pragma unroll
    for (int nt = 0; nt < 2; ++nt) {
        int n = nbase + nt * 16 + l16;
#pragma unroll
        for (int ks = 0; ks < NK; ++ks)
            f[ks][nt] = *(const f16x8*)(wt + n * Kp + ks * 32 + q * 8);
    }
}

// Layers 0/1 over MH 16-row groups: D' = W^T X^T; relu'd f16 to H (stride 136).
template <int NK0, int MH>
DI void l01(const f16x8 (*w0f)[2], const f16x8 (*w1f)[2],
            const _Float16* __restrict__ X, int xstride,
            _Float16* __restrict__ H0, _Float16* __restrict__ H1,
            int l16, int w, int q) {
    const f32x4 zero = {0.f, 0.f, 0.f, 0.f};
    f32x4 acc[2][MH];
#pragma unroll
    for (int nt = 0; nt < 2; ++nt)
#pragma unroll
        for (int mt = 0; mt < MH; ++mt) acc[nt][mt] = zero;
#pragma unroll
    for (int ks = 0; ks < NK0; ++ks) {
        f16x8 x[MH];
#pragma unroll
        for (int mt = 0; mt < MH; ++mt)
            x[mt] = *(const f16x8*)(X + (mt * 16 + l16) * xstride + ks * 32 + q * 8);
#pragma unroll
        for (int nt = 0; nt < 2; ++nt)
#pragma unroll
            for (int mt = 0; mt < MH; ++mt)
                acc[nt][mt] = mfma16(w0f[ks][nt], x[mt], acc[nt][mt]);
    }
#pragma unroll
    for (int mt = 0; mt < MH; ++mt)
#pragma unroll
        for (int nt = 0; nt < 2; ++nt) {
            f16x4 h;
#pragma unroll
            for (int i = 0; i < 4; ++i) h[i] = (_Float16)fmaxf(acc[nt][mt][i], 0.f);
            *(f16x4*)(H0 + (mt * 16 + l16) * 136 + w * 32 + nt * 16 + q * 4) = h;
        }
    BAR();  // after this barrier X is dead; H1 (aliased to X) may be written
    f32x4 a1[2][MH];
#pragma unroll
    for (int nt = 0; nt < 2; ++nt)
#pragma unroll
        for (int mt = 0; mt < MH; ++mt) a1[nt][mt] = zero;
#pragma unroll
    for (int ks = 0; ks < 4; ++ks) {
        f16x8 x[MH];
#pragma unroll
        for (int mt = 0; mt < MH; ++mt)
            x[mt] = *(const f16x8*)(H0 + (mt * 16 + l16) * 136 + ks * 32 + q * 8);
#pragma unroll
        for (int nt = 0; nt < 2; ++nt)
#pragma unroll
            for (int mt = 0; mt < MH; ++mt)
                a1[nt][mt] = mfma16(w1f[ks][nt], x[mt], a1[nt][mt]);
    }
#pragma unroll
    for (int mt = 0; mt < MH; ++mt)
#pragma unroll
        for (int nt = 0; nt < 2; ++nt) {
            f16x4 h;
#pragma unroll
            for (int i = 0; i < 4; ++i) h[i] = (_Float16)fmaxf(a1[nt][mt][i], 0.f);
            *(f16x4*)(H1 + (mt * 16 + l16) * 136 + w * 32 + nt * 16 + q * 4) = h;
        }
    BAR();
}

// Layer 2, row group g: rows (w>>1)*16 + l16 + 32*g, cols (w&1)*16 + q*4 + i.
DI f32x4 l2g(const f16x8* w2f, const _Float16* __restrict__ H1, int l16, int w,
             int q, int g) {
    int m = (w >> 1) * 16 + l16 + 32 * g;
    f32x4 acc = {0.f, 0.f, 0.f, 0.f};
#pragma unroll
    for (int ks = 0; ks < 4; ++ks) {
        f16x8 x = *(const f16x8*)(H1 + m * 136 + ks * 32 + q * 8);
        acc = mfma16(w2f[ks], x, acc);
    }
    return acc;
}

// ---------------- weight prep: fp32 [K][N] -> f16 W^T [Np][Kp] (zero padded) ----
struct WPtrs { const float* p[15]; };

__global__ void k_prep(WPtrs wp, _Float16* __restrict__ ws) {
    int b = blockIdx.x;
    const float* src; int K, N, Np, Kp, off;
    if (b == 0)       { src = wp.p[0];  K = 3;   N = 128; Np = 128; Kp = 32;  off = 0; }
    else if (b == 1)  { src = wp.p[1];  K = 128; N = 128; Np = 128; Kp = 128; off = 4096; }
    else if (b == 2)  { src = wp.p[2];  K = 128; N = 32;  Np = 32;  Kp = 128; off = 20480; }
    else if (b == 3)  { src = wp.p[3];  K = 3;   N = 128; Np = 128; Kp = 32;  off = 24576; }
    else if (b == 4)  { src = wp.p[4];  K = 128; N = 128; Np = 128; Kp = 128; off = 28672; }
    else if (b == 5)  { src = wp.p[5];  K = 128; N = 32;  Np = 32;  Kp = 128; off = 45056; }
    else if (b <= 9)  { int t = b - 6;  src = wp.p[6] + t * 12288;  K = 96;  N = 128; Np = 128; Kp = 96;  off = 49152 + t * 32768; }
    else if (b <= 13) { int t = b - 10; src = wp.p[7] + t * 16384;  K = 128; N = 128; Np = 128; Kp = 128; off = 61440 + t * 32768; }
    else if (b <= 17) { int t = b - 14; src = wp.p[8] + t * 4096;   K = 128; N = 32;  Np = 32;  Kp = 128; off = 77824 + t * 32768; }
    else if (b <= 21) { int t = b - 18; src = wp.p[9] + t * 8192;   K = 64;  N = 128; Np = 128; Kp = 64;  off = 180224 + t * 28672; }
    else if (b <= 25) { int t = b - 22; src = wp.p[10] + t * 16384; K = 128; N = 128; Np = 128; Kp = 128; off = 188416 + t * 28672; }
    else if (b <= 29) { int t = b - 26; src = wp.p[11] + t * 4096;  K = 128; N = 32;  Np = 32;  Kp = 128; off = 204800 + t * 28672; }
    else if (b == 30) { src = wp.p[12]; K = 32;  N = 128; Np = 128; Kp = 32;  off = 294912; }
    else if (b == 31) { src = wp.p[13]; K = 128; N = 128; Np = 128; Kp = 128; off = 299008; }
    else              { src = wp.p[14]; K = 128; N = 1;   Np = 16;  Kp = 128; off = 315392; }
    int total = Np * Kp;
    for (int i = threadIdx.x; i < total; i += 256) {
        int n = i / Kp, k = i - n * Kp;
        float v = (k < K && n < N) ? src[k * N + n] : 0.f;
        ws[off + i] = (_Float16)v;
    }
}

// ---------------- CSR build: histogram -> scan -> scatter (u32 atomics only) -----
__global__ void k_zero(unsigned* __restrict__ p, int n) {
    int i = blockIdx.x * 256 + threadIdx.x;
    if (i < n) p[i] = 0u;
}
__global__ void k_hist(const int* __restrict__ gi, unsigned* __restrict__ cnt) {
    int e = blockIdx.x * 256 + threadIdx.x;
    if (e < 512000) atomicAdd(&cnt[gi[2 * e + 1]], 1u);
}
// one block, 1024 threads: exclusive scan of cnt[0..32000) via Kogge-Stone.
__global__ __launch_bounds__(1024) void k_scan(
    const unsigned* __restrict__ cnt, unsigned* __restrict__ rowptr,
    unsigned* __restrict__ cursor) {
    __shared__ unsigned s[1024];
    int t = threadIdx.x;
    unsigned loc[32];
    unsigned sum = 0;
#pragma unroll
    for (int i = 0; i < 32; ++i) {
        int idx = t * 32 + i;
        unsigned v = (idx < 32000) ? cnt[idx] : 0u;
        loc[i] = v; sum += v;
    }
    s[t] = sum;
    __syncthreads();
#pragma unroll
    for (int d = 1; d < 1024; d <<= 1) {
        unsigned x = (t >= d) ? s[t - d] : 0u;
        __syncthreads();
        s[t] += x;
        __syncthreads();
    }
    if (t == 1023) rowptr[32000] = s[1023];
    unsigned off = (t == 0) ? 0u : s[t - 1];
#pragma unroll
    for (int i = 0; i < 32; ++i) {
        int idx = t * 32 + i;
        if (idx < 32000) { rowptr[idx] = off; cursor[idx] = off; off += loc[i]; }
    }
}
__global__ void k_scatter(const int* __restrict__ gi, unsigned* __restrict__ cursor,
                          unsigned* __restrict__ iperm, int2* __restrict__ sr) {
    int e = blockIdx.x * 256 + threadIdx.x;
    if (e < 512000) {
        int s = gi[2 * e], r = gi[2 * e + 1];
        unsigned pos = atomicAdd(&cursor[r], 1u);
        iperm[pos] = (unsigned)e;
        sr[pos] = make_int2(s, r);
    }
}

// ---------------- encoder: fp32 [M][3] -> MLP -> f16 out rows (64-row tiles) -----
// Xp aliases H1 -> restage the full padded row every tile (1 chunk/thread).
__global__ __launch_bounds__(256, 4) void k_enc(
    const float* __restrict__ in, _Float16* __restrict__ out,
    const _Float16* __restrict__ w0t, const _Float16* __restrict__ w1t,
    const _Float16* __restrict__ w2t, int NT, const unsigned* __restrict__ iperm) {
    __shared__ __align__(16) _Float16 H0[64 * 136];
    __shared__ __align__(16) _Float16 H1s[64 * 136];
    _Float16* const Xp = H1s;  // stride 40, lifetime before l01's first barrier
    const int tid = threadIdx.x, w = tid >> 6, lane = tid & 63;
    const int q = lane >> 4, l16 = lane & 15;
    f16x8 w0f[1][2], w1f[4][2], w2f[4];
    load_wf2<1>(w0t, 32, w * 32, l16, q, w0f);
    load_wf2<4>(w1t, 128, w * 32, l16, q, w1f);
    {
        int n2 = (w & 1) * 16 + l16;
#pragma unroll
        for (int ks = 0; ks < 4; ++ks)
            w2f[ks] = *(const f16x8*)(w2t + n2 * 128 + ks * 32 + q * 8);
    }
    const int g = gridDim.x;
    const int cr = tid >> 2, csx = tid & 3;  // 4 chunks of 8 f16 per row
    const int orow = (w >> 1) * 16 + l16, ocol = (w & 1) * 16 + q * 4;
    int t = blockIdx.x;

    while (true) {
        f16x8 h;
#pragma unroll
        for (int i = 0; i < 8; ++i) h[i] = (_Float16)0.f;
        if (csx == 0) {
            unsigned e = iperm ? iperm[t * 64 + cr] : (unsigned)(t * 64 + cr);
            h[0] = (_Float16)in[e * 3 + 0];
            h[1] = (_Float16)in[e * 3 + 1];
            h[2] = (_Float16)in[e * 3 + 2];
        }
        *(f16x8*)(Xp + cr * 40 + csx * 8) = h;
        BAR();
        l01<1, 4>(w0f, w1f, Xp, 40, H0, H1s, l16, w, q);
#pragma unroll
        for (int gg = 0; gg < 2; ++gg) {
            f32x4 o = l2g(w2f, H1s, l16, w, q, gg);
            f16x4 ov;
#pragma unroll
            for (int i = 0; i < 4; ++i) ov[i] = (_Float16)o[i];
            *(f16x4*)(out + (t * 64 + gg * 32 + orow) * 32 + ocol) = ov;
        }
        t += g;
        if (t >= NT) break;
        BAR();  // H1s reads (l2) must finish before next tile's Xp stage
    }
}

// ---------------- edge update: [edge|node_s|node_r](96) -> MLP -> +res -----------
// 64-row tiles, f16 latents, receiver-sorted rows, sequential sr. Xe aliases H1.
// Residual's old value read from LDS (Xe cols 0..31) after the staging barrier.
__global__ __launch_bounds__(256, 4) void k_edge(
    const _Float16* __restrict__ node, _Float16* __restrict__ edgeP,
    const int2* __restrict__ sr,
    const _Float16* __restrict__ w0t, const _Float16* __restrict__ w1t,
    const _Float16* __restrict__ w2t) {
    __shared__ __align__(16) _Float16 H0[64 * 136];
    __shared__ __align__(16) _Float16 H1s[64 * 136];
    _Float16* const Xe = H1s;  // stride 104, lifetime before l01's first barrier
    const int tid = threadIdx.x, w = tid >> 6, lane = tid & 63;
    const int q = lane >> 4, l16 = lane & 15;
    f16x8 w0f[3][2], w1f[4][2], w2f[4];
    load_wf2<3>(w0t, 96, w * 32, l16, q, w0f);
    load_wf2<4>(w1t, 128, w * 32, l16, q, w1f);
    {
        int n2 = (w & 1) * 16 + l16;
#pragma unroll
        for (int ks = 0; ks < 4; ++ks)
            w2f[ks] = *(const f16x8*)(w2t + n2 * 128 + ks * 32 + q * 8);
    }
    int cr[3], cs[3];
#pragma unroll
    for (int j = 0; j < 3; ++j) {
        int c = tid + 256 * j;
        cr[j] = c / 12; cs[j] = c - cr[j] * 12;
    }
    const int orow = (w >> 1) * 16 + l16, ocol = (w & 1) * 16 + q * 4;

    const int NT = 8000, g = gridDim.x;
    int t = blockIdx.x;

    while (true) {
        int2 srv[3];
#pragma unroll
        for (int j = 0; j < 3; ++j) srv[j] = sr[t * 64 + cr[j]];
        int4 v[3];
#pragma unroll
        for (int j = 0; j < 3; ++j) {
            int s = cs[j];
            const _Float16* src = (s < 4) ? edgeP + (t * 64 + cr[j]) * 32 + s * 8
                               : (s < 8) ? node + srv[j].x * 32 + (s - 4) * 8
                                         : node + srv[j].y * 32 + (s - 8) * 8;
            v[j] = *(const int4*)src;
        }
#pragma unroll
        for (int j = 0; j < 3; ++j)
            *(int4*)(Xe + cr[j] * 104 + cs[j] * 8) = v[j];
        BAR();
        // old edge latent from LDS (cols 0..31 of the staged tile)
        f16x4 oldv[2];
#pragma unroll
        for (int gg = 0; gg < 2; ++gg)
            oldv[gg] = *(const f16x4*)(Xe + (gg * 32 + orow) * 104 + ocol);

        l01<3, 4>(w0f, w1f, Xe, 104, H0, H1s, l16, w, q);
#pragma unroll
        for (int gg = 0; gg < 2; ++gg) {
            f32x4 o = l2g(w2f, H1s, l16, w, q, gg);
            f16x4 nv;
#pragma unroll
            for (int i = 0; i < 4; ++i) nv[i] = (_Float16)(o[i] + (float)oldv[gg][i]);
            *(f16x4*)(edgeP + (t * 64 + gg * 32 + orow) * 32 + ocol) = nv;
        }

        t += g;
        if (t >= NT) break;
        BAR();  // H1s reads (l2) must finish before next tile's Xe stage
    }
}

// ---------------- node update: [node|csr_sum(edgeP)](64) -> MLP -> +res ----------
// One 64-row tile per block. Aggregation = contiguous fp32 segment sum (f16 rows).
// Xn aliases H1. Old node latent read from LDS (Xn cols 0..31).
__global__ __launch_bounds__(256, 4) void k_node(
    _Float16* __restrict__ node, const _Float16* __restrict__ edgeP,
    const unsigned* __restrict__ rowptr,
    const _Float16* __restrict__ w0t, const _Float16* __restrict__ w1t,
    const _Float16* __restrict__ w2t) {
    __shared__ __align__(16) _Float16 H0[64 * 136];
    __shared__ __align__(16) _Float16 H1s[64 * 136];
    _Float16* const Xn = H1s;  // stride 72
    const int tid = threadIdx.x, w = tid >> 6, lane = tid & 63;
    const int q = lane >> 4, l16 = lane & 15;
    f16x8 w0f[2][2], w1f[4][2], w2f[4];
    load_wf2<2>(w0t, 64, w * 32, l16, q, w0f);
    load_wf2<4>(w1t, 128, w * 32, l16, q, w1f);
    {
        int n2 = (w & 1) * 16 + l16;
#pragma unroll
        for (int ks = 0; ks < 4; ++ks)
            w2f[ks] = *(const f16x8*)(w2t + n2 * 128 + ks * 32 + q * 8);
    }
    const int t = blockIdx.x;
    const int orow = (w >> 1) * 16 + l16, ocol = (w & 1) * 16 + q * 4;
    // 8 chunks/row (16 B each): cs<4 node copy, cs>=4 segment-sum of edgeP chunk.
    // 64 rows x 8 = 512 chunks = 2 per thread.
#pragma unroll
    for (int j = 0; j < 2; ++j) {
        int c = tid + 256 * j;
        int cr = c >> 3, cs = c & 7;
        int r = t * 64 + cr;
        if (cs < 4) {
            *(int4*)(Xn + cr * 72 + cs * 8) = *(const int4*)(node + r * 32 + cs * 8);
        } else {
            unsigned b = rowptr[r], e = rowptr[r + 1];
            const _Float16* base = edgeP + (cs - 4) * 8;
            float a0[8], a1[8];
#pragma unroll
            for (int i = 0; i < 8; ++i) { a0[i] = 0.f; a1[i] = 0.f; }
            unsigned p = b;
            for (; p + 2 <= e; p += 2) {
                f16x8 x0 = *(const f16x8*)(base + (p + 0) * 32);
                f16x8 x1 = *(const f16x8*)(base + (p + 1) * 32);
#pragma unroll
                for (int i = 0; i < 8; ++i) { a0[i] += (float)x0[i]; a1[i] += (float)x1[i]; }
            }
            if (p < e) {
                f16x8 x0 = *(const f16x8*)(base + p * 32);
#pragma unroll
                for (int i = 0; i < 8; ++i) a0[i] += (float)x0[i];
            }
            f16x8 h;
#pragma unroll
            for (int i = 0; i < 8; ++i) h[i] = (_Float16)(a0[i] + a1[i]);
            *(f16x8*)(Xn + cr * 72 + cs * 8) = h;
        }
    }
    BAR();
    f16x4 oldv[2];
#pragma unroll
    for (int gg = 0; gg < 2; ++gg)
        oldv[gg] = *(const f16x4*)(Xn + (gg * 32 + orow) * 72 + ocol);
    l01<2, 4>(w0f, w1f, Xn, 72, H0, H1s, l16, w, q);
#pragma unroll
    for (int gg = 0; gg < 2; ++gg) {
        f32x4 o = l2g(w2f, H1s, l16, w, q, gg);
        f16x4 nv;
#pragma unroll
        for (int i = 0; i < 4; ++i) nv[i] = (_Float16)(o[i] + (float)oldv[gg][i]);
        *(f16x4*)(node + (t * 64 + gg * 32 + orow) * 32 + ocol) = nv;
    }
}

// ---------------- decoder: node(32) -> MLP(32->128->128->1) -> fp32 out ----------
__global__ __launch_bounds__(256, 4) void k_dec(
    const _Float16* __restrict__ node,
    const _Float16* __restrict__ w0t, const _Float16* __restrict__ w1t,
    const _Float16* __restrict__ w2t, float* __restrict__ out) {
    __shared__ __align__(16) _Float16 H0[64 * 136];
    __shared__ __align__(16) _Float16 H1s[64 * 136];
    _Float16* const Xd = H1s;  // stride 40
    const int tid = threadIdx.x, w = tid >> 6, lane = tid & 63;
    const int q = lane >> 4, l16 = lane & 15;
    f16x8 w0f[1][2], w1f[4][2], w2f[4];
    load_wf2<1>(w0t, 32, w * 32, l16, q, w0f);
    load_wf2<4>(w1t, 128, w * 32, l16, q, w1f);
    {
        int n2 = l16;  // padded W2^T is [16][128]; all waves load tile 0
#pragma unroll
        for (int ks = 0; ks < 4; ++ks)
            w2f[ks] = *(const f16x8*)(w2t + n2 * 128 + ks * 32 + q * 8);
    }
    const int t = blockIdx.x;
    {
        int cr = tid >> 2, cs = tid & 3;
        *(int4*)(Xd + cr * 40 + cs * 8) = *(const int4*)(node + (t * 64 + cr) * 32 + cs * 8);
    }
    BAR();
    l01<1, 4>(w0f, w1f, Xd, 40, H0, H1s, l16, w, q);
#pragma unroll
    for (int gg = 0; gg < 2; ++gg) {
        f32x4 o = l2g(w2f, H1s, l16, w, q, gg);
        // only col 0 is real: waves with (w&1)==0, lanes q==0, reg 0
        if ((w & 1) == 0 && q == 0) out[t * 64 + gg * 32 + (w >> 1) * 16 + l16] = o[0];
    }
}

extern "C" void kernel_launch(void* const* d_in, const int* in_sizes, int n_in,
                              void* d_out, int out_size, void* d_ws, size_t ws_size,
                              hipStream_t stream) {
    const float* input_node = (const float*)d_in[0];
    const float* input_edge = (const float*)d_in[1];
    const int* gi = (const int*)d_in[2];

    _Float16* ws = (_Float16*)d_ws;
    // ws layout (bytes):
    //   weights f16:         [0,          634,880)
    //   node  f16 32000x32:  [655,360,    2,703,360)
    //   edgeP f16 512000x32: [2,703,360,  35,471,360)   (receiver-sorted rows)
    //   rowptr u32[32001]:   [35,471,360, 35,599,364)
    //   cursor u32[32000]:   [35,599,616, 35,727,616)
    //   iperm  u32[512000]:  [35,727,616, 37,775,616)
    //   sr   int2[512000]:   [37,775,616, 41,871,616)
    _Float16* node = (_Float16*)((char*)d_ws + 655360);
    _Float16* edgeP = (_Float16*)((char*)d_ws + 2703360);
    unsigned* rowptr = (unsigned*)((char*)d_ws + 35471360);
    unsigned* cursor = (unsigned*)((char*)d_ws + 35599616);
    unsigned* iperm = (unsigned*)((char*)d_ws + 35727616);
    int2* sr = (int2*)((char*)d_ws + 37775616);

    WPtrs wp;
    for (int i = 0; i < 15; ++i) wp.p[i] = (const float*)d_in[3 + i];

    k_prep<<<33, 256, 0, stream>>>(wp, ws);

    // CSR build (u32 atomics only)
    k_zero<<<125, 256, 0, stream>>>(cursor, 32000);
    k_hist<<<2000, 256, 0, stream>>>(gi, cursor);
    k_scan<<<1, 1024, 0, stream>>>(cursor, rowptr, cursor);
    k_scatter<<<2000, 256, 0, stream>>>(gi, cursor, iperm, sr);

    k_enc<<<500, 256, 0, stream>>>(input_node, node, ws + 0, ws + 4096, ws + 20480,
                                   500, nullptr);
    k_enc<<<1024, 256, 0, stream>>>(input_edge, edgeP, ws + 24576, ws + 28672,
                                    ws + 45056, 8000, iperm);

    for (int t = 0; t < 4; ++t) {
        k_edge<<<1024, 256, 0, stream>>>(node, edgeP, sr,
                                         ws + 49152 + t * 32768,
                                         ws + 61440 + t * 32768,
                                         ws + 77824 + t * 32768);
        k_node<<<500, 256, 0, stream>>>(node, edgeP, rowptr,
                                        ws + 180224 + t * 28672,
                                        ws + 188416 + t * 28672,
                                        ws + 204800 + t * 28672);
    }
    k_dec<<<500, 256, 0, stream>>>(node, ws + 294912, ws + 299008, ws + 315392,
                                   (float*)d_out);
}

// Round 13
// 503.823 us; speedup vs baseline: 1.2100x; 1.2100x over previous
//
#include <hip/hip_runtime.h>

typedef __attribute__((ext_vector_type(8))) _Float16 f16x8;
typedef __attribute__((ext_vector_type(4))) _Float16 f16x4;
typedef __attribute__((ext_vector_type(4))) float f32x4;

#define DI __device__ __forceinline__
// Raw barrier: LDS-drain only (lgkmcnt). Avoids the compiler's vmcnt(0) drain.
#define BAR() asm volatile("s_waitcnt lgkmcnt(0)\n\ts_barrier" ::: "memory")

DI f32x4 mfma16(f16x8 a, f16x8 b, f32x4 c) {
    return __builtin_amdgcn_mfma_f32_16x16x32_f16(a, b, c, 0, 0, 0);
}

// Wave-mapping: wave w owns features [w*32, w*32+32) for layers 0/1 (2 n-tiles,
// weight frags reused across all MH m-groups of 16 rows). Layer 2: wave w computes
// rows (w>>1)*16 (+32*g) and cols (w&1)*16 of the MHx16 x 32 output.
// PROVEN STATE (R10, 504 us): lb(256,3), 64-row k_edge/k_enc/k_dec, 32-row k_node.
// R11 lesson: lb(256,4) caps regs at 128 -> weights evicted -> regression.
// R12 lesson: 64-row k_node diverged intermittently under graph replay -> revert.

template <int NK>
DI void load_wf2(const _Float16* __restrict__ wt, int Kp, int nbase, int l16, int q,
                 f16x8 f[NK][2]) {
#pragma unroll
    for (int nt = 0; nt < 2; ++nt) {
        int n = nbase + nt * 16 + l16;
#pragma unroll
        for (int ks = 0; ks < NK; ++ks)
            f[ks][nt] = *(const f16x8*)(wt + n * Kp + ks * 32 + q * 8);
    }
}

// Layers 0/1 over MH 16-row groups: D' = W^T X^T; relu'd f16 to H (stride 136).
template <int NK0, int MH>
DI void l01(const f16x8 (*w0f)[2], const f16x8 (*w1f)[2],
            const _Float16* __restrict__ X, int xstride,
            _Float16* __restrict__ H0, _Float16* __restrict__ H1,
            int l16, int w, int q) {
    const f32x4 zero = {0.f, 0.f, 0.f, 0.f};
    f32x4 acc[2][MH];
#pragma unroll
    for (int nt = 0; nt < 2; ++nt)
#pragma unroll
        for (int mt = 0; mt < MH; ++mt) acc[nt][mt] = zero;
#pragma unroll
    for (int ks = 0; ks < NK0; ++ks) {
        f16x8 x[MH];
#pragma unroll
        for (int mt = 0; mt < MH; ++mt)
            x[mt] = *(const f16x8*)(X + (mt * 16 + l16) * xstride + ks * 32 + q * 8);
#pragma unroll
        for (int nt = 0; nt < 2; ++nt)
#pragma unroll
            for (int mt = 0; mt < MH; ++mt)
                acc[nt][mt] = mfma16(w0f[ks][nt], x[mt], acc[nt][mt]);
    }
#pragma unroll
    for (int mt = 0; mt < MH; ++mt)
#pragma unroll
        for (int nt = 0; nt < 2; ++nt) {
            f16x4 h;
#pragma unroll
            for (int i = 0; i < 4; ++i) h[i] = (_Float16)fmaxf(acc[nt][mt][i], 0.f);
            *(f16x4*)(H0 + (mt * 16 + l16) * 136 + w * 32 + nt * 16 + q * 4) = h;
        }
    BAR();
    f32x4 a1[2][MH];
#pragma unroll
    for (int nt = 0; nt < 2; ++nt)
#pragma unroll
        for (int mt = 0; mt < MH; ++mt) a1[nt][mt] = zero;
#pragma unroll
    for (int ks = 0; ks < 4; ++ks) {
        f16x8 x[MH];
#pragma unroll
        for (int mt = 0; mt < MH; ++mt)
            x[mt] = *(const f16x8*)(H0 + (mt * 16 + l16) * 136 + ks * 32 + q * 8);
#pragma unroll
        for (int nt = 0; nt < 2; ++nt)
#pragma unroll
            for (int mt = 0; mt < MH; ++mt)
                a1[nt][mt] = mfma16(w1f[ks][nt], x[mt], a1[nt][mt]);
    }
#pragma unroll
    for (int mt = 0; mt < MH; ++mt)
#pragma unroll
        for (int nt = 0; nt < 2; ++nt) {
            f16x4 h;
#pragma unroll
            for (int i = 0; i < 4; ++i) h[i] = (_Float16)fmaxf(a1[nt][mt][i], 0.f);
            *(f16x4*)(H1 + (mt * 16 + l16) * 136 + w * 32 + nt * 16 + q * 4) = h;
        }
    BAR();
}

// Layer 2, row group g: rows (w>>1)*16 + l16 + 32*g, cols (w&1)*16 + q*4 + i.
DI f32x4 l2g(const f16x8* w2f, const _Float16* __restrict__ H1, int l16, int w,
             int q, int g) {
    int m = (w >> 1) * 16 + l16 + 32 * g;
    f32x4 acc = {0.f, 0.f, 0.f, 0.f};
#pragma unroll
    for (int ks = 0; ks < 4; ++ks) {
        f16x8 x = *(const f16x8*)(H1 + m * 136 + ks * 32 + q * 8);
        acc = mfma16(w2f[ks], x, acc);
    }
    return acc;
}

// ---------------- weight prep: fp32 [K][N] -> f16 W^T [Np][Kp] (zero padded) ----
struct WPtrs { const float* p[15]; };

__global__ void k_prep(WPtrs wp, _Float16* __restrict__ ws) {
    int b = blockIdx.x;
    const float* src; int K, N, Np, Kp, off;
    if (b == 0)       { src = wp.p[0];  K = 3;   N = 128; Np = 128; Kp = 32;  off = 0; }
    else if (b == 1)  { src = wp.p[1];  K = 128; N = 128; Np = 128; Kp = 128; off = 4096; }
    else if (b == 2)  { src = wp.p[2];  K = 128; N = 32;  Np = 32;  Kp = 128; off = 20480; }
    else if (b == 3)  { src = wp.p[3];  K = 3;   N = 128; Np = 128; Kp = 32;  off = 24576; }
    else if (b == 4)  { src = wp.p[4];  K = 128; N = 128; Np = 128; Kp = 128; off = 28672; }
    else if (b == 5)  { src = wp.p[5];  K = 128; N = 32;  Np = 32;  Kp = 128; off = 45056; }
    else if (b <= 9)  { int t = b - 6;  src = wp.p[6] + t * 12288;  K = 96;  N = 128; Np = 128; Kp = 96;  off = 49152 + t * 32768; }
    else if (b <= 13) { int t = b - 10; src = wp.p[7] + t * 16384;  K = 128; N = 128; Np = 128; Kp = 128; off = 61440 + t * 32768; }
    else if (b <= 17) { int t = b - 14; src = wp.p[8] + t * 4096;   K = 128; N = 32;  Np = 32;  Kp = 128; off = 77824 + t * 32768; }
    else if (b <= 21) { int t = b - 18; src = wp.p[9] + t * 8192;   K = 64;  N = 128; Np = 128; Kp = 64;  off = 180224 + t * 28672; }
    else if (b <= 25) { int t = b - 22; src = wp.p[10] + t * 16384; K = 128; N = 128; Np = 128; Kp = 128; off = 188416 + t * 28672; }
    else if (b <= 29) { int t = b - 26; src = wp.p[11] + t * 4096;  K = 128; N = 32;  Np = 32;  Kp = 128; off = 204800 + t * 28672; }
    else if (b == 30) { src = wp.p[12]; K = 32;  N = 128; Np = 128; Kp = 32;  off = 294912; }
    else if (b == 31) { src = wp.p[13]; K = 128; N = 128; Np = 128; Kp = 128; off = 299008; }
    else              { src = wp.p[14]; K = 128; N = 1;   Np = 16;  Kp = 128; off = 315392; }
    int total = Np * Kp;
    for (int i = threadIdx.x; i < total; i += 256) {
        int n = i / Kp, k = i - n * Kp;
        float v = (k < K && n < N) ? src[k * N + n] : 0.f;
        ws[off + i] = (_Float16)v;
    }
}

// ---------------- CSR build: histogram -> scan -> scatter (u32 atomics only) -----
__global__ void k_zero(unsigned* __restrict__ p, int n) {
    int i = blockIdx.x * 256 + threadIdx.x;
    if (i < n) p[i] = 0u;
}
__global__ void k_hist(const int* __restrict__ gi, unsigned* __restrict__ cnt) {
    int e = blockIdx.x * 256 + threadIdx.x;
    if (e < 512000) atomicAdd(&cnt[gi[2 * e + 1]], 1u);
}
// one block, 1024 threads: exclusive scan of cnt[0..32000) via Kogge-Stone.
__global__ __launch_bounds__(1024) void k_scan(
    const unsigned* __restrict__ cnt, unsigned* __restrict__ rowptr,
    unsigned* __restrict__ cursor) {
    __shared__ unsigned s[1024];
    int t = threadIdx.x;
    unsigned loc[32];
    unsigned sum = 0;
#pragma unroll
    for (int i = 0; i < 32; ++i) {
        int idx = t * 32 + i;
        unsigned v = (idx < 32000) ? cnt[idx] : 0u;
        loc[i] = v; sum += v;
    }
    s[t] = sum;
    __syncthreads();
#pragma unroll
    for (int d = 1; d < 1024; d <<= 1) {
        unsigned x = (t >= d) ? s[t - d] : 0u;
        __syncthreads();
        s[t] += x;
        __syncthreads();
    }
    if (t == 1023) rowptr[32000] = s[1023];
    unsigned off = (t == 0) ? 0u : s[t - 1];
#pragma unroll
    for (int i = 0; i < 32; ++i) {
        int idx = t * 32 + i;
        if (idx < 32000) { rowptr[idx] = off; cursor[idx] = off; off += loc[i]; }
    }
}
__global__ void k_scatter(const int* __restrict__ gi, unsigned* __restrict__ cursor,
                          unsigned* __restrict__ iperm, int2* __restrict__ sr) {
    int e = blockIdx.x * 256 + threadIdx.x;
    if (e < 512000) {
        int s = gi[2 * e], r = gi[2 * e + 1];
        unsigned pos = atomicAdd(&cursor[r], 1u);
        iperm[pos] = (unsigned)e;
        sr[pos] = make_int2(s, r);
    }
}

// ---------------- encoder: fp32 [M][3] -> MLP -> f16 out rows (64-row tiles) -----
__global__ __launch_bounds__(256, 3) void k_enc(
    const float* __restrict__ in, _Float16* __restrict__ out,
    const _Float16* __restrict__ w0t, const _Float16* __restrict__ w1t,
    const _Float16* __restrict__ w2t, int NT, const unsigned* __restrict__ iperm) {
    __shared__ __align__(16) _Float16 Xp[64 * 40];
    __shared__ __align__(16) _Float16 H0[64 * 136];
    __shared__ __align__(16) _Float16 H1[64 * 136];
    const int tid = threadIdx.x, w = tid >> 6, lane = tid & 63;
    const int q = lane >> 4, l16 = lane & 15;
    f16x8 w0f[1][2], w1f[4][2], w2f[4];
    load_wf2<1>(w0t, 32, w * 32, l16, q, w0f);
    load_wf2<4>(w1t, 128, w * 32, l16, q, w1f);
    {
        int n2 = (w & 1) * 16 + l16;
#pragma unroll
        for (int ks = 0; ks < 4; ++ks)
            w2f[ks] = *(const f16x8*)(w2t + n2 * 128 + ks * 32 + q * 8);
    }
    for (int c = tid; c < 2560; c += 256) Xp[c] = (_Float16)0.f;
    BAR();

    const int g = gridDim.x;
    const int dr = tid / 3, dc = tid - dr * 3;  // valid when tid<192
    const int orow = (w >> 1) * 16 + l16, ocol = (w & 1) * 16 + q * 4;
    int t = blockIdx.x;

    while (true) {
        if (tid < 192) {
            unsigned e = iperm ? iperm[t * 64 + dr] : (unsigned)(t * 64 + dr);
            Xp[dr * 40 + dc] = (_Float16)in[e * 3 + dc];
        }
        BAR();
        l01<1, 4>(w0f, w1f, Xp, 40, H0, H1, l16, w, q);
#pragma unroll
        for (int gg = 0; gg < 2; ++gg) {
            f32x4 o = l2g(w2f, H1, l16, w, q, gg);
            f16x4 ov;
#pragma unroll
            for (int i = 0; i < 4; ++i) ov[i] = (_Float16)o[i];
            *(f16x4*)(out + (t * 64 + gg * 32 + orow) * 32 + ocol) = ov;
        }
        t += g;
        if (t >= NT) break;
    }
}

// ---------------- edge update: [edge|node_s|node_r](96) -> MLP -> +res -----------
// 64-row tiles, f16 latents, receiver-sorted rows, sequential sr. No data pipeline
// (registers are the scarce resource: weights stay resident). sr one tile ahead.
// Residual's old value is read from LDS (Xe cols 0..31) after the staging barrier.
__global__ __launch_bounds__(256, 3) void k_edge(
    const _Float16* __restrict__ node, _Float16* __restrict__ edgeP,
    const int2* __restrict__ sr,
    const _Float16* __restrict__ w0t, const _Float16* __restrict__ w1t,
    const _Float16* __restrict__ w2t) {
    __shared__ __align__(16) _Float16 Xe[64 * 104];
    __shared__ __align__(16) _Float16 H0[64 * 136];
    __shared__ __align__(16) _Float16 H1[64 * 136];
    const int tid = threadIdx.x, w = tid >> 6, lane = tid & 63;
    const int q = lane >> 4, l16 = lane & 15;
    f16x8 w0f[3][2], w1f[4][2], w2f[4];
    load_wf2<3>(w0t, 96, w * 32, l16, q, w0f);
    load_wf2<4>(w1t, 128, w * 32, l16, q, w1f);
    {
        int n2 = (w & 1) * 16 + l16;
#pragma unroll
        for (int ks = 0; ks < 4; ++ks)
            w2f[ks] = *(const f16x8*)(w2t + n2 * 128 + ks * 32 + q * 8);
    }
    int cr[3], cs[3];
#pragma unroll
    for (int j = 0; j < 3; ++j) {
        int c = tid + 256 * j;
        cr[j] = c / 12; cs[j] = c - cr[j] * 12;
    }
    const int orow = (w >> 1) * 16 + l16, ocol = (w & 1) * 16 + q * 4;

    const int NT = 8000, g = gridDim.x;
    int t = blockIdx.x;
    int2 srv[3];
#pragma unroll
    for (int j = 0; j < 3; ++j) srv[j] = sr[t * 64 + cr[j]];

    while (true) {
        int tn = t + g; if (tn >= NT) tn = t;
        // stage tile t (loads issue; Xe write waits on them via vmcnt)
        int4 v[3];
#pragma unroll
        for (int j = 0; j < 3; ++j) {
            int s = cs[j];
            const _Float16* src = (s < 4) ? edgeP + (t * 64 + cr[j]) * 32 + s * 8
                               : (s < 8) ? node + srv[j].x * 32 + (s - 4) * 8
                                         : node + srv[j].y * 32 + (s - 8) * 8;
            v[j] = *(const int4*)src;
        }
        int2 srn[3];
#pragma unroll
        for (int j = 0; j < 3; ++j) srn[j] = sr[tn * 64 + cr[j]];
#pragma unroll
        for (int j = 0; j < 3; ++j)
            *(int4*)(Xe + cr[j] * 104 + cs[j] * 8) = v[j];
        BAR();
        // old edge latent from LDS (cols 0..31 of the staged tile)
        f16x4 oldv[2];
#pragma unroll
        for (int gg = 0; gg < 2; ++gg)
            oldv[gg] = *(const f16x4*)(Xe + (gg * 32 + orow) * 104 + ocol);

        l01<3, 4>(w0f, w1f, Xe, 104, H0, H1, l16, w, q);
#pragma unroll
        for (int gg = 0; gg < 2; ++gg) {
            f32x4 o = l2g(w2f, H1, l16, w, q, gg);
            f16x4 nv;
#pragma unroll
            for (int i = 0; i < 4; ++i) nv[i] = (_Float16)(o[i] + (float)oldv[gg][i]);
            *(f16x4*)(edgeP + (t * 64 + gg * 32 + orow) * 32 + ocol) = nv;
        }

        if (tn == t) break;
        t = tn;
#pragma unroll
        for (int j = 0; j < 3; ++j) srv[j] = srn[j];
    }
}

// ---------------- node update: [node|csr_sum(edgeP)](64) -> MLP -> +res ----------
// One 32-row tile per block (proven variant). Aggregation = contiguous fp32
// segment sum over f16 rows. Old node latent read from LDS (Xn cols 0..31).
__global__ __launch_bounds__(256, 3) void k_node(
    _Float16* __restrict__ node, const _Float16* __restrict__ edgeP,
    const unsigned* __restrict__ rowptr,
    const _Float16* __restrict__ w0t, const _Float16* __restrict__ w1t,
    const _Float16* __restrict__ w2t) {
    __shared__ __align__(16) _Float16 Xn[32 * 72];
    __shared__ __align__(16) _Float16 H0[32 * 136];
    __shared__ __align__(16) _Float16 H1[32 * 136];
    const int tid = threadIdx.x, w = tid >> 6, lane = tid & 63;
    const int q = lane >> 4, l16 = lane & 15;
    f16x8 w0f[2][2], w1f[4][2], w2f[4];
    load_wf2<2>(w0t, 64, w * 32, l16, q, w0f);
    load_wf2<4>(w1t, 128, w * 32, l16, q, w1f);
    {
        int n2 = (w & 1) * 16 + l16;
#pragma unroll
        for (int ks = 0; ks < 4; ++ks)
            w2f[ks] = *(const f16x8*)(w2t + n2 * 128 + ks * 32 + q * 8);
    }
    const int t = blockIdx.x;
    const int orow = (w >> 1) * 16 + l16, ocol = (w & 1) * 16 + q * 4;
    // 8 chunks/row (16 B each): cs<4 node copy, cs>=4 segment-sum of edgeP chunk
    {
        int cr = tid >> 3, cs = tid & 7;
        int r = t * 32 + cr;
        if (cs < 4) {
            *(int4*)(Xn + cr * 72 + cs * 8) = *(const int4*)(node + r * 32 + cs * 8);
        } else {
            unsigned b = rowptr[r], e = rowptr[r + 1];
            const _Float16* base = edgeP + (cs - 4) * 8;
            float a0[8], a1[8];
#pragma unroll
            for (int i = 0; i < 8; ++i) { a0[i] = 0.f; a1[i] = 0.f; }
            unsigned p = b;
            for (; p + 2 <= e; p += 2) {
                f16x8 x0 = *(const f16x8*)(base + (p + 0) * 32);
                f16x8 x1 = *(const f16x8*)(base + (p + 1) * 32);
#pragma unroll
                for (int i = 0; i < 8; ++i) { a0[i] += (float)x0[i]; a1[i] += (float)x1[i]; }
            }
            if (p < e) {
                f16x8 x0 = *(const f16x8*)(base + p * 32);
#pragma unroll
                for (int i = 0; i < 8; ++i) a0[i] += (float)x0[i];
            }
            f16x8 h;
#pragma unroll
            for (int i = 0; i < 8; ++i) h[i] = (_Float16)(a0[i] + a1[i]);
            *(f16x8*)(Xn + cr * 72 + cs * 8) = h;
        }
    }
    BAR();
    f16x4 oldv = *(const f16x4*)(Xn + orow * 72 + ocol);
    l01<2, 2>(w0f, w1f, Xn, 72, H0, H1, l16, w, q);
    f32x4 o = l2g(w2f, H1, l16, w, q, 0);
    f16x4 nv;
#pragma unroll
    for (int i = 0; i < 4; ++i) nv[i] = (_Float16)(o[i] + (float)oldv[i]);
    *(f16x4*)(node + (t * 32 + orow) * 32 + ocol) = nv;
}

// ---------------- decoder: node(32) -> MLP(32->128->128->1) -> fp32 out ----------
__global__ __launch_bounds__(256, 3) void k_dec(
    const _Float16* __restrict__ node,
    const _Float16* __restrict__ w0t, const _Float16* __restrict__ w1t,
    const _Float16* __restrict__ w2t, float* __restrict__ out) {
    __shared__ __align__(16) _Float16 Xd[64 * 40];
    __shared__ __align__(16) _Float16 H0[64 * 136];
    __shared__ __align__(16) _Float16 H1[64 * 136];
    const int tid = threadIdx.x, w = tid >> 6, lane = tid & 63;
    const int q = lane >> 4, l16 = lane & 15;
    f16x8 w0f[1][2], w1f[4][2], w2f[4];
    load_wf2<1>(w0t, 32, w * 32, l16, q, w0f);
    load_wf2<4>(w1t, 128, w * 32, l16, q, w1f);
    {
        int n2 = l16;  // padded W2^T is [16][128]; all waves load tile 0
#pragma unroll
        for (int ks = 0; ks < 4; ++ks)
            w2f[ks] = *(const f16x8*)(w2t + n2 * 128 + ks * 32 + q * 8);
    }
    const int t = blockIdx.x;
    {
        int cr = tid >> 2, cs = tid & 3;
        *(int4*)(Xd + cr * 40 + cs * 8) = *(const int4*)(node + (t * 64 + cr) * 32 + cs * 8);
    }
    BAR();
    l01<1, 4>(w0f, w1f, Xd, 40, H0, H1, l16, w, q);
#pragma unroll
    for (int gg = 0; gg < 2; ++gg) {
        f32x4 o = l2g(w2f, H1, l16, w, q, gg);
        // only col 0 is real: waves with (w&1)==0, lanes q==0, reg 0
        if ((w & 1) == 0 && q == 0) out[t * 64 + gg * 32 + (w >> 1) * 16 + l16] = o[0];
    }
}

extern "C" void kernel_launch(void* const* d_in, const int* in_sizes, int n_in,
                              void* d_out, int out_size, void* d_ws, size_t ws_size,
                              hipStream_t stream) {
    const float* input_node = (const float*)d_in[0];
    const float* input_edge = (const float*)d_in[1];
    const int* gi = (const int*)d_in[2];

    _Float16* ws = (_Float16*)d_ws;
    // ws layout (bytes):
    //   weights f16:         [0,          634,880)
    //   node  f16 32000x32:  [655,360,    2,703,360)
    //   edgeP f16 512000x32: [2,703,360,  35,471,360)   (receiver-sorted rows)
    //   rowptr u32[32001]:   [35,471,360, 35,599,364)
    //   cursor u32[32000]:   [35,599,616, 35,727,616)
    //   iperm  u32[512000]:  [35,727,616, 37,775,616)
    //   sr   int2[512000]:   [37,775,616, 41,871,616)
    _Float16* node = (_Float16*)((char*)d_ws + 655360);
    _Float16* edgeP = (_Float16*)((char*)d_ws + 2703360);
    unsigned* rowptr = (unsigned*)((char*)d_ws + 35471360);
    unsigned* cursor = (unsigned*)((char*)d_ws + 35599616);
    unsigned* iperm = (unsigned*)((char*)d_ws + 35727616);
    int2* sr = (int2*)((char*)d_ws + 37775616);

    WPtrs wp;
    for (int i = 0; i < 15; ++i) wp.p[i] = (const float*)d_in[3 + i];

    k_prep<<<33, 256, 0, stream>>>(wp, ws);

    // CSR build (u32 atomics only)
    k_zero<<<125, 256, 0, stream>>>(cursor, 32000);
    k_hist<<<2000, 256, 0, stream>>>(gi, cursor);
    k_scan<<<1, 1024, 0, stream>>>(cursor, rowptr, cursor);
    k_scatter<<<2000, 256, 0, stream>>>(gi, cursor, iperm, sr);

    k_enc<<<500, 256, 0, stream>>>(input_node, node, ws + 0, ws + 4096, ws + 20480,
                                   500, nullptr);
    k_enc<<<768, 256, 0, stream>>>(input_edge, edgeP, ws + 24576, ws + 28672,
                                   ws + 45056, 8000, iperm);

    for (int t = 0; t < 4; ++t) {
        k_edge<<<768, 256, 0, stream>>>(node, edgeP, sr,
                                        ws + 49152 + t * 32768,
                                        ws + 61440 + t * 32768,
                                        ws + 77824 + t * 32768);
        k_node<<<1000, 256, 0, stream>>>(node, edgeP, rowptr,
                                         ws + 180224 + t * 28672,
                                         ws + 188416 + t * 28672,
                                         ws + 204800 + t * 28672);
    }
    k_dec<<<500, 256, 0, stream>>>(node, ws + 294912, ws + 299008, ws + 315392,
                                   (float*)d_out);
}